// Round 9
// baseline (286.372 us; speedup 1.0000x reference)
//
#include <hip/hip_runtime.h>

#define NFEAT   128
#define NHID    64
#define NLAYER  3
#define NNODES  50000
#define NEDGES  800000
#define NGRAPHS 512
#define BN_EPS  1e-5f
#define NPART   3125          // blocks in gemm/mlp grid (50000/16)
#define CAP     64            // fixed CSR row capacity (max deg ~45 for Poisson(16))

typedef unsigned short u16;
__device__ inline float b2f(u16 v) { return __uint_as_float(((unsigned)v) << 16); }
__device__ inline u16 f2b(float f) {
    unsigned u = __float_as_uint(f);
    return (u16)((u + 0x7FFF + ((u >> 16) & 1)) >> 16);   // RN-even
}

// ---------------------------------------------------------------- fused CSR fill (XCD-range partitioned)
__global__ __launch_bounds__(256) void k_fill(const int* __restrict__ ei,
                                              int* __restrict__ deg,
                                              int* __restrict__ col) {
    int rangeId = blockIdx.x & 7, chunk = blockIdx.x >> 3;
    int lo = rangeId * (NNODES / 8), hi = lo + (NNODES / 8);
    int ebeg = chunk * (NEDGES / 256), eend = ebeg + (NEDGES / 256);
    for (int e = ebeg + threadIdx.x; e < eend; e += 256) {
        int dst = ei[NEDGES + e];
        if (dst >= lo && dst < hi) {
            int slot = atomicAdd(&deg[dst], 1);
            if (slot < CAP) col[dst * CAP + slot] = ei[e];
        }
    }
}

// ---------------------------------------------------------------- graph start offsets (batch sorted)
__global__ __launch_bounds__(256) void k_goff(const int* __restrict__ batch,
                                              int* __restrict__ gstart) {
    int gph = blockIdx.x * 256 + threadIdx.x;
    if (gph > NGRAPHS) return;
    if (gph == NGRAPHS) { gstart[NGRAPHS] = NNODES; return; }
    int lo = 0, hi = NNODES;
    while (lo < hi) {
        int mid = (lo + hi) >> 1;
        if (batch[mid] < gph) lo = mid + 1; else hi = mid;
    }
    gstart[gph] = lo;
}

// ---------------------------------------------------------------- input GEMM -> z0 (bf16) + stats partials
__global__ __launch_bounds__(256) void k_gemm_in(const float* __restrict__ x,
                                                 const float* __restrict__ Wt,
                                                 const float* __restrict__ bt,
                                                 u16* __restrict__ zout,
                                                 float* __restrict__ partials) {
    __shared__ float sW[NFEAT * NHID];   // 32 KB
    __shared__ float sx[16 * NFEAT];     // 8 KB
    __shared__ float ps[4][128];         // 2 KB
    int tid = threadIdx.x;
    const float4* W4 = (const float4*)Wt;
    float4* sW4 = (float4*)sW;
#pragma unroll
    for (int i = 0; i < NFEAT * NHID / 4 / 256; ++i) sW4[i * 256 + tid] = W4[i * 256 + tid];
    int base = blockIdx.x * 16;
    const float4* x4 = (const float4*)(x + (long long)base * NFEAT);
    float4* sx4 = (float4*)sx;
#pragma unroll
    for (int i = 0; i < 16 * NFEAT / 4 / 256; ++i) sx4[i * 256 + tid] = x4[i * 256 + tid];
    __syncthreads();
    int j = tid & 63, q = tid >> 6;
    float b = bt[j];
    float acc[4] = {b, b, b, b};
    for (int k = 0; k < NFEAT; ++k) {
        float wv = sW[k * NHID + j];
#pragma unroll
        for (int i = 0; i < 4; ++i) acc[i] += sx[(q * 4 + i) * NFEAT + k] * wv;
    }
    float s1 = 0.f, s2 = 0.f;
#pragma unroll
    for (int i = 0; i < 4; ++i) {
        zout[(base + q * 4 + i) * NHID + j] = f2b(acc[i]);
        s1 += acc[i];
        s2 += acc[i] * acc[i];
    }
    ps[q][j] = s1;
    ps[q][64 + j] = s2;
    __syncthreads();
    if (tid < 128)
        partials[blockIdx.x * 128 + tid] = ps[0][tid] + ps[1][tid] + ps[2][tid] + ps[3][tid];
}

// ---------------------------------------------------------------- reduce partials -> stats[128] (sum | sumsq)
__global__ __launch_bounds__(256) void k_red(const float* __restrict__ partials,
                                             float* __restrict__ stats) {
    __shared__ float red[4];
    int c = blockIdx.x, t = threadIdx.x;
    float s = 0.f;
    for (int i = t; i < NPART; i += 256) s += partials[i * 128 + c];
#pragma unroll
    for (int off = 32; off >= 1; off >>= 1) s += __shfl_xor(s, off, 64);
    if ((t & 63) == 0) red[t >> 6] = s;
    __syncthreads();
    if (t == 0) stats[c] = red[0] + red[1] + red[2] + red[3];
}

// ---------------------------------------------------------------- h = (relu?) bn(z), bf16 -> bf16 streaming
template <int RELU>
__global__ __launch_bounds__(256) void k_bnh(const u16* __restrict__ z,
                                             const float* __restrict__ stats,
                                             const float* __restrict__ gamma,
                                             const float* __restrict__ beta,
                                             u16* __restrict__ h) {
    int idx = blockIdx.x * 256 + threadIdx.x;       // ushort4 index
    int j0 = (idx & 15) * 4;
    ushort4 v = ((const ushort4*)z)[idx];
    float o[4] = {b2f(v.x), b2f(v.y), b2f(v.z), b2f(v.w)};
#pragma unroll
    for (int k = 0; k < 4; ++k) {
        int j = j0 + k;
        float m = stats[j] * (1.0f / NNODES);
        float var = stats[64 + j] * (1.0f / NNODES) - m * m;
        float sc = rsqrtf(var + BN_EPS) * gamma[j];
        float val = (o[k] - m) * sc + beta[j];
        if (RELU) val = fmaxf(val, 0.f);
        o[k] = val;
    }
    ushort4 w;
    w.x = f2b(o[0]); w.y = f2b(o[1]); w.z = f2b(o[2]); w.w = f2b(o[3]);
    ((ushort4*)h)[idx] = w;
}

// ---------------------------------------------------------------- pool per graph: mean of h rows
__global__ __launch_bounds__(256) void k_pool(const u16* __restrict__ h,
                                              const int* __restrict__ gstart,
                                              float* __restrict__ out) {
    __shared__ float red[4][64];
    int gph = blockIdx.x;
    int j = threadIdx.x & 63, sub = threadIdx.x >> 6;
    int s0 = gstart[gph], e0 = gstart[gph + 1];
    float s = 0.f;
    for (int r = s0 + sub; r < e0; r += 4) s += b2f(h[r * NHID + j]);
    red[sub][j] = s;
    __syncthreads();
    if (sub == 0) {
        s = red[0][j] + red[1][j] + red[2][j] + red[3][j];
        out[gph * NHID + j] = s / fmaxf((float)(e0 - s0), 1.0f);
    }
}

// ---------------------------------------------------------------- fused gather + MLP: z' = relu((h+Σh)@W1+b1)@W2+b2
__global__ __launch_bounds__(256) void k_mlp(const u16* __restrict__ hB,
                                             const int* __restrict__ deg,
                                             const int* __restrict__ col,
                                             const float* __restrict__ W1,
                                             const float* __restrict__ b1,
                                             const float* __restrict__ W2,
                                             const float* __restrict__ b2,
                                             u16* __restrict__ zout,
                                             float* __restrict__ partials) {
    __shared__ float sW[NHID * NHID];    // 16 KB, W1 then W2
    __shared__ float sz[16][68];         // 4.25 KB
    __shared__ float ps[4][128];         // 2 KB
    int tid = threadIdx.x;
    {
        const float4* W14 = (const float4*)W1;
        float4* s4 = (float4*)sW;
#pragma unroll
        for (int i = 0; i < 4; ++i) s4[i * 256 + tid] = W14[i * 256 + tid];
    }
    int w = tid >> 6, lane = tid & 63;
    int q = lane >> 4, c = lane & 15;
    int node = w * 4 + q;
    int base = blockIdx.x * 16;
    int r = base + node;
    const ushort4* h8 = (const ushort4*)hB;

    // gather: quarter-wave per node, bf16 rows (8 B/lane), unroll-4
    float acc[4], aB[4] = {0, 0, 0, 0}, aC[4] = {0, 0, 0, 0}, aD[4] = {0, 0, 0, 0};
    {
        ushort4 v = h8[r * 16 + c];       // self
        acc[0] = b2f(v.x); acc[1] = b2f(v.y); acc[2] = b2f(v.z); acc[3] = b2f(v.w);
    }
    {
        int dd = deg[r]; if (dd > CAP) dd = CAP;
        int t = r * CAP, tend = r * CAP + dd;
        for (; t + 4 <= tend; t += 4) {
            int s0 = col[t], s1 = col[t + 1], s2 = col[t + 2], s3 = col[t + 3];
            ushort4 v0 = h8[s0 * 16 + c];
            ushort4 v1 = h8[s1 * 16 + c];
            ushort4 v2 = h8[s2 * 16 + c];
            ushort4 v3 = h8[s3 * 16 + c];
            acc[0] += b2f(v0.x); acc[1] += b2f(v0.y); acc[2] += b2f(v0.z); acc[3] += b2f(v0.w);
            aB[0] += b2f(v1.x); aB[1] += b2f(v1.y); aB[2] += b2f(v1.z); aB[3] += b2f(v1.w);
            aC[0] += b2f(v2.x); aC[1] += b2f(v2.y); aC[2] += b2f(v2.z); aC[3] += b2f(v2.w);
            aD[0] += b2f(v3.x); aD[1] += b2f(v3.y); aD[2] += b2f(v3.z); aD[3] += b2f(v3.w);
        }
        for (; t < tend; ++t) {
            ushort4 v0 = h8[col[t] * 16 + c];
            acc[0] += b2f(v0.x); acc[1] += b2f(v0.y); acc[2] += b2f(v0.z); acc[3] += b2f(v0.w);
        }
    }
    *(float4*)&sz[node][c * 4] = make_float4(acc[0] + aB[0] + aC[0] + aD[0],
                                             acc[1] + aB[1] + aC[1] + aD[1],
                                             acc[2] + aB[2] + aC[2] + aD[2],
                                             acc[3] + aB[3] + aC[3] + aD[3]);
    __syncthreads();   // W1 staged + sz visible

    int row0 = w * 4;
    float bb = b1[lane];
    float acc1[4] = {bb, bb, bb, bb};
    for (int k = 0; k < NHID; ++k) {
        float wv = sW[k * NHID + lane];
#pragma unroll
        for (int n = 0; n < 4; ++n) acc1[n] += sz[row0 + n][k] * wv;
    }
    __syncthreads();   // all done reading W1
    {
        const float4* W24 = (const float4*)W2;
        float4* s4 = (float4*)sW;
#pragma unroll
        for (int i = 0; i < 4; ++i) s4[i * 256 + tid] = W24[i * 256 + tid];
    }
#pragma unroll
    for (int n = 0; n < 4; ++n) sz[row0 + n][lane] = fmaxf(acc1[n], 0.f);
    __syncthreads();   // W2 staged

    float bb2 = b2[lane];
    float acc2[4] = {bb2, bb2, bb2, bb2};
    for (int k = 0; k < NHID; ++k) {
        float wv = sW[k * NHID + lane];
#pragma unroll
        for (int n = 0; n < 4; ++n) acc2[n] += sz[row0 + n][k] * wv;
    }
    float s1 = 0.f, s2 = 0.f;
#pragma unroll
    for (int n = 0; n < 4; ++n) {
        zout[(base + row0 + n) * NHID + lane] = f2b(acc2[n]);
        s1 += acc2[n];
        s2 += acc2[n] * acc2[n];
    }
    ps[w][lane] = s1;
    ps[w][64 + lane] = s2;
    __syncthreads();
    if (tid < 128)
        partials[blockIdx.x * 128 + tid] = ps[0][tid] + ps[1][tid] + ps[2][tid] + ps[3][tid];
}

// ----------------------------------------------------------------
extern "C" void kernel_launch(void* const* d_in, const int* in_sizes, int n_in,
                              void* d_out, int out_size, void* d_ws, size_t ws_size,
                              hipStream_t stream) {
    const float* x     = (const float*)d_in[0];
    const int*   ei    = (const int*)d_in[1];
    const int*   batch = (const int*)d_in[2];
    const float* Wt    = (const float*)d_in[3];
    const float* bt    = (const float*)d_in[4];
    const float* gt    = (const float*)d_in[5];
    const float* bet   = (const float*)d_in[6];
    const float* W1    = (const float*)d_in[7];
    const float* b1    = (const float*)d_in[8];
    const float* W2    = (const float*)d_in[9];
    const float* b2    = (const float*)d_in[10];
    const float* g     = (const float*)d_in[11];
    const float* be    = (const float*)d_in[12];
    float* out = (float*)d_out;

    float* partials = (float*)d_ws;                 // 3125*128 f32
    float* stats    = partials + NPART * 128;       // 4 x 128 f32
    int* deg        = (int*)(stats + 4 * 128);      // 50000
    int* col        = deg + NNODES;                 // 50000*64
    int* gstart     = col + NNODES * CAP;           // 514 (padded even for 8B align)
    u16* zB         = (u16*)(gstart + 514);         // 50000*64 bf16
    u16* hB         = zB + NNODES * NHID;           // 50000*64 bf16

    hipMemsetAsync(deg, 0, NNODES * sizeof(int), stream);

    // CSR build + graph offsets
    k_fill<<<2048, 256, 0, stream>>>(ei, deg, col);
    k_goff<<<3, 256, 0, stream>>>(batch, gstart);

    // stage 0: input transform -> z0 (bf16), stats, h0 = bn(z0) (no relu), pool
    k_gemm_in<<<NPART, 256, 0, stream>>>(x, Wt, bt, zB, partials);
    k_red<<<128, 256, 0, stream>>>(partials, stats);
    k_bnh<0><<<NPART, 256, 0, stream>>>(zB, stats, gt, bet, hB);
    k_pool<<<NGRAPHS, 256, 0, stream>>>(hB, gstart, out);

    for (int l = 0; l < NLAYER; ++l) {
        float* st_out = stats + (l + 1) * 128;
        k_mlp<<<NPART, 256, 0, stream>>>(hB, deg, col,
                                         W1 + l * NHID * NHID, b1 + l * NHID,
                                         W2 + l * NHID * NHID, b2 + l * NHID, zB, partials);
        k_red<<<128, 256, 0, stream>>>(partials, st_out);
        k_bnh<1><<<NPART, 256, 0, stream>>>(zB, st_out, g + l * NHID, be + l * NHID, hB);
        k_pool<<<NGRAPHS, 256, 0, stream>>>(hB, gstart, out + (l + 1) * NGRAPHS * NHID);
    }
}

// Round 10
// 264.358 us; speedup vs baseline: 1.0833x; 1.0833x over previous
//
#include <hip/hip_runtime.h>

#define NFEAT   128
#define NHID    64
#define NLAYER  3
#define NNODES  50000
#define NEDGES  800000
#define NGRAPHS 512
#define BN_EPS  1e-5f
#define NPART   3125          // blocks in gemm/mlp grid (50000/16)
#define CAP     64            // fixed CSR row capacity (max deg ~45 for Poisson(16))

typedef unsigned short u16;
__device__ inline float b2f(u16 v) { return __uint_as_float(((unsigned)v) << 16); }
__device__ inline u16 f2b(float f) {
    unsigned u = __float_as_uint(f);
    return (u16)((u + 0x7FFF + ((u >> 16) & 1)) >> 16);   // RN-even
}

// ---------------------------------------------------------------- fused CSR fill (XCD-range partitioned)
__global__ __launch_bounds__(256) void k_fill(const int* __restrict__ ei,
                                              int* __restrict__ deg,
                                              int* __restrict__ col) {
    int rangeId = blockIdx.x & 7, chunk = blockIdx.x >> 3;
    int lo = rangeId * (NNODES / 8), hi = lo + (NNODES / 8);
    int ebeg = chunk * (NEDGES / 256), eend = ebeg + (NEDGES / 256);
    for (int e = ebeg + threadIdx.x; e < eend; e += 256) {
        int dst = ei[NEDGES + e];
        if (dst >= lo && dst < hi) {
            int slot = atomicAdd(&deg[dst], 1);
            if (slot < CAP) col[dst * CAP + slot] = ei[e];
        }
    }
}

// ---------------------------------------------------------------- graph start offsets (batch sorted)
__global__ __launch_bounds__(256) void k_goff(const int* __restrict__ batch,
                                              int* __restrict__ gstart) {
    int gph = blockIdx.x * 256 + threadIdx.x;
    if (gph > NGRAPHS) return;
    if (gph == NGRAPHS) { gstart[NGRAPHS] = NNODES; return; }
    int lo = 0, hi = NNODES;
    while (lo < hi) {
        int mid = (lo + hi) >> 1;
        if (batch[mid] < gph) lo = mid + 1; else hi = mid;
    }
    gstart[gph] = lo;
}

// ---------------------------------------------------------------- input GEMM -> z0 (bf16) + stats partials
__global__ __launch_bounds__(256) void k_gemm_in(const float* __restrict__ x,
                                                 const float* __restrict__ Wt,
                                                 const float* __restrict__ bt,
                                                 u16* __restrict__ zout,
                                                 float* __restrict__ partials) {
    __shared__ float sW[NFEAT * NHID];   // 32 KB
    __shared__ float sx[16 * NFEAT];     // 8 KB
    __shared__ float ps[4][128];         // 2 KB
    int tid = threadIdx.x;
    const float4* W4 = (const float4*)Wt;
    float4* sW4 = (float4*)sW;
#pragma unroll
    for (int i = 0; i < NFEAT * NHID / 4 / 256; ++i) sW4[i * 256 + tid] = W4[i * 256 + tid];
    int base = blockIdx.x * 16;
    const float4* x4 = (const float4*)(x + (long long)base * NFEAT);
    float4* sx4 = (float4*)sx;
#pragma unroll
    for (int i = 0; i < 16 * NFEAT / 4 / 256; ++i) sx4[i * 256 + tid] = x4[i * 256 + tid];
    __syncthreads();
    int j = tid & 63, q = tid >> 6;
    float b = bt[j];
    float acc[4] = {b, b, b, b};
    for (int k = 0; k < NFEAT; ++k) {
        float wv = sW[k * NHID + j];
#pragma unroll
        for (int i = 0; i < 4; ++i) acc[i] += sx[(q * 4 + i) * NFEAT + k] * wv;
    }
    float s1 = 0.f, s2 = 0.f;
#pragma unroll
    for (int i = 0; i < 4; ++i) {
        zout[(base + q * 4 + i) * NHID + j] = f2b(acc[i]);
        s1 += acc[i];
        s2 += acc[i] * acc[i];
    }
    ps[q][j] = s1;
    ps[q][64 + j] = s2;
    __syncthreads();
    if (tid < 128)
        partials[blockIdx.x * 128 + tid] = ps[0][tid] + ps[1][tid] + ps[2][tid] + ps[3][tid];
}

// ---------------------------------------------------------------- reduce partials -> stats[128] (sum | sumsq)
__global__ __launch_bounds__(256) void k_red(const float* __restrict__ partials,
                                             float* __restrict__ stats) {
    __shared__ float red[4];
    int c = blockIdx.x, t = threadIdx.x;
    float s = 0.f;
    for (int i = t; i < NPART; i += 256) s += partials[i * 128 + c];
#pragma unroll
    for (int off = 32; off >= 1; off >>= 1) s += __shfl_xor(s, off, 64);
    if ((t & 63) == 0) red[t >> 6] = s;
    __syncthreads();
    if (t == 0) stats[c] = red[0] + red[1] + red[2] + red[3];
}

// ---------------------------------------------------------------- pool per graph, BN applied on the fly (bf16 z)
template <int RELU>
__global__ __launch_bounds__(256) void k_pool(const u16* __restrict__ z,
                                              const float* __restrict__ stats,
                                              const float* __restrict__ gamma,
                                              const float* __restrict__ beta,
                                              const int* __restrict__ gstart,
                                              float* __restrict__ out) {
    __shared__ float red[4][64];
    int gph = blockIdx.x;
    int j = threadIdx.x & 63, sub = threadIdx.x >> 6;
    float m = stats[j] * (1.0f / NNODES);
    float var = stats[64 + j] * (1.0f / NNODES) - m * m;
    float sc = rsqrtf(var + BN_EPS) * gamma[j];
    float sh = beta[j] - m * sc;
    int s0 = gstart[gph], e0 = gstart[gph + 1];
    float s = 0.f;
    for (int r = s0 + sub; r < e0; r += 4) {
        float v = fmaf(b2f(z[r * NHID + j]), sc, sh);
        if (RELU) v = fmaxf(v, 0.f);
        s += v;
    }
    red[sub][j] = s;
    __syncthreads();
    if (sub == 0) {
        s = red[0][j] + red[1][j] + red[2][j] + red[3][j];
        out[gph * NHID + j] = s / fmaxf((float)(e0 - s0), 1.0f);
    }
}

// ---------------------------------------------------------------- fused gather(+inline BN) + MLP + stats partials
template <int RELU_IN>
__global__ __launch_bounds__(256) void k_mlp(const u16* __restrict__ zin,
                                             const float* __restrict__ stats,
                                             const float* __restrict__ gamma,
                                             const float* __restrict__ beta,
                                             const int* __restrict__ deg,
                                             const int* __restrict__ col,
                                             const float* __restrict__ W1,
                                             const float* __restrict__ b1,
                                             const float* __restrict__ W2,
                                             const float* __restrict__ b2,
                                             u16* __restrict__ zout,
                                             float* __restrict__ partials) {
    __shared__ float sW[NHID * NHID];    // 16 KB, W1 then W2
    __shared__ float sz[16][68];         // 4.25 KB
    __shared__ float ps[4][128];         // 2 KB
    int tid = threadIdx.x;
    {
        const float4* W14 = (const float4*)W1;
        float4* s4 = (float4*)sW;
#pragma unroll
        for (int i = 0; i < 4; ++i) s4[i * 256 + tid] = W14[i * 256 + tid];
    }
    int w = tid >> 6, lane = tid & 63;
    int q = lane >> 4, c = lane & 15;
    int node = w * 4 + q;
    int base = blockIdx.x * 16;
    int r = base + node;
    const ushort4* h8 = (const ushort4*)zin;

    // BN coefficients for this lane's 4 features
    int j0 = c * 4;
    float sc[4], sh[4];
#pragma unroll
    for (int k = 0; k < 4; ++k) {
        int j = j0 + k;
        float m = stats[j] * (1.0f / NNODES);
        float var = stats[64 + j] * (1.0f / NNODES) - m * m;
        sc[k] = rsqrtf(var + BN_EPS) * gamma[j];
        sh[k] = beta[j] - m * sc[k];
    }

#define BN1(vv, kk, dstv)                                  \
    {                                                      \
        float u = fmaf(b2f(vv), sc[kk], sh[kk]);           \
        if (RELU_IN) u = fmaxf(u, 0.f);                    \
        dstv += u;                                         \
    }
#define BN4(v4, dst)                                       \
    BN1(v4.x, 0, dst[0]) BN1(v4.y, 1, dst[1])              \
    BN1(v4.z, 2, dst[2]) BN1(v4.w, 3, dst[3])

    // gather: quarter-wave per node, bf16 rows (8 B/lane), 8 loads in flight
    float aA[4] = {0, 0, 0, 0}, aB[4] = {0, 0, 0, 0};
    {
        ushort4 v = h8[r * 16 + c];       // self (also BN'd)
        BN4(v, aA)
    }
    {
        int dd = deg[r]; if (dd > CAP) dd = CAP;
        const int* cp = col + r * CAP;
        int t = 0;
        for (; t + 8 <= dd; t += 8) {
            int s0 = cp[t],     s1 = cp[t + 1], s2 = cp[t + 2], s3 = cp[t + 3];
            int s4 = cp[t + 4], s5 = cp[t + 5], s6 = cp[t + 6], s7 = cp[t + 7];
            ushort4 v0 = h8[s0 * 16 + c];
            ushort4 v1 = h8[s1 * 16 + c];
            ushort4 v2 = h8[s2 * 16 + c];
            ushort4 v3 = h8[s3 * 16 + c];
            ushort4 v4 = h8[s4 * 16 + c];
            ushort4 v5 = h8[s5 * 16 + c];
            ushort4 v6 = h8[s6 * 16 + c];
            ushort4 v7 = h8[s7 * 16 + c];
            BN4(v0, aA) BN4(v1, aB) BN4(v2, aA) BN4(v3, aB)
            BN4(v4, aA) BN4(v5, aB) BN4(v6, aA) BN4(v7, aB)
        }
        for (; t < dd; ++t) {
            ushort4 v0 = h8[cp[t] * 16 + c];
            BN4(v0, aA)
        }
    }
#undef BN4
#undef BN1
    *(float4*)&sz[node][c * 4] = make_float4(aA[0] + aB[0], aA[1] + aB[1],
                                             aA[2] + aB[2], aA[3] + aB[3]);
    __syncthreads();   // W1 staged + sz visible

    int row0 = w * 4;
    float bb = b1[lane];
    float acc1[4] = {bb, bb, bb, bb};
    for (int k = 0; k < NHID; ++k) {
        float wv = sW[k * NHID + lane];
#pragma unroll
        for (int n = 0; n < 4; ++n) acc1[n] += sz[row0 + n][k] * wv;
    }
    __syncthreads();   // all done reading W1
    {
        const float4* W24 = (const float4*)W2;
        float4* s4 = (float4*)sW;
#pragma unroll
        for (int i = 0; i < 4; ++i) s4[i * 256 + tid] = W24[i * 256 + tid];
    }
#pragma unroll
    for (int n = 0; n < 4; ++n) sz[row0 + n][lane] = fmaxf(acc1[n], 0.f);
    __syncthreads();   // W2 staged

    float bb2 = b2[lane];
    float acc2[4] = {bb2, bb2, bb2, bb2};
    for (int k = 0; k < NHID; ++k) {
        float wv = sW[k * NHID + lane];
#pragma unroll
        for (int n = 0; n < 4; ++n) acc2[n] += sz[row0 + n][k] * wv;
    }
    float s1 = 0.f, s2 = 0.f;
#pragma unroll
    for (int n = 0; n < 4; ++n) {
        zout[(base + row0 + n) * NHID + lane] = f2b(acc2[n]);
        s1 += acc2[n];
        s2 += acc2[n] * acc2[n];
    }
    ps[w][lane] = s1;
    ps[w][64 + lane] = s2;
    __syncthreads();
    if (tid < 128)
        partials[blockIdx.x * 128 + tid] = ps[0][tid] + ps[1][tid] + ps[2][tid] + ps[3][tid];
}

// ----------------------------------------------------------------
extern "C" void kernel_launch(void* const* d_in, const int* in_sizes, int n_in,
                              void* d_out, int out_size, void* d_ws, size_t ws_size,
                              hipStream_t stream) {
    const float* x     = (const float*)d_in[0];
    const int*   ei    = (const int*)d_in[1];
    const int*   batch = (const int*)d_in[2];
    const float* Wt    = (const float*)d_in[3];
    const float* bt    = (const float*)d_in[4];
    const float* gt    = (const float*)d_in[5];
    const float* bet   = (const float*)d_in[6];
    const float* W1    = (const float*)d_in[7];
    const float* b1    = (const float*)d_in[8];
    const float* W2    = (const float*)d_in[9];
    const float* b2    = (const float*)d_in[10];
    const float* g     = (const float*)d_in[11];
    const float* be    = (const float*)d_in[12];
    float* out = (float*)d_out;

    u16* A          = (u16*)d_ws;                   // 50000*64 bf16
    u16* B          = A + NNODES * NHID;            // 50000*64 bf16
    float* partials = (float*)(B + NNODES * NHID);  // 3125*128 f32
    float* stats    = partials + NPART * 128;       // 4 x 128 f32
    int* deg        = (int*)(stats + 4 * 128);      // 50000
    int* col        = deg + NNODES;                 // 50000*64
    int* gstart     = col + NNODES * CAP;           // 513

    hipMemsetAsync(deg, 0, NNODES * sizeof(int), stream);

    // CSR build + graph offsets
    k_fill<<<2048, 256, 0, stream>>>(ei, deg, col);
    k_goff<<<3, 256, 0, stream>>>(batch, gstart);

    // stage 0: input transform -> z0 (bf16) + stats + pool (BN inline, no relu)
    k_gemm_in<<<NPART, 256, 0, stream>>>(x, Wt, bt, A, partials);
    k_red<<<128, 256, 0, stream>>>(partials, stats);
    k_pool<0><<<NGRAPHS, 256, 0, stream>>>(A, stats, gt, bet, gstart, out);

    u16* bufs[2] = {A, B};
    const float* gam[4] = {gt, g, g + NHID, g + 2 * NHID};
    const float* bet_[4] = {bet, be, be + NHID, be + 2 * NHID};
    for (int l = 0; l < NLAYER; ++l) {
        u16* zin  = bufs[l & 1];
        u16* zout = bufs[(l + 1) & 1];
        float* st_in  = stats + l * 128;
        float* st_out = stats + (l + 1) * 128;
        if (l == 0)
            k_mlp<0><<<NPART, 256, 0, stream>>>(zin, st_in, gam[l], bet_[l], deg, col,
                                                W1 + l * NHID * NHID, b1 + l * NHID,
                                                W2 + l * NHID * NHID, b2 + l * NHID, zout, partials);
        else
            k_mlp<1><<<NPART, 256, 0, stream>>>(zin, st_in, gam[l], bet_[l], deg, col,
                                                W1 + l * NHID * NHID, b1 + l * NHID,
                                                W2 + l * NHID * NHID, b2 + l * NHID, zout, partials);
        k_red<<<128, 256, 0, stream>>>(partials, st_out);
        k_pool<1><<<NGRAPHS, 256, 0, stream>>>(zout, st_out, gam[l + 1], bet_[l + 1], gstart,
                                               out + (l + 1) * NGRAPHS * NHID);
    }
}

// Round 11
// 237.613 us; speedup vs baseline: 1.2052x; 1.1126x over previous
//
#include <hip/hip_runtime.h>

#define NFEAT   128
#define NHID    64
#define NLAYER  3
#define NNODES  50000
#define NEDGES  800000
#define NGRAPHS 512
#define BN_EPS  1e-5f
#define NPART   3125          // blocks in gemm/mlp grid (50000/16)
#define CAP     64            // fixed CSR row capacity (max deg ~45 for Poisson(16))
#define PADW    68            // u16 row pad: 136B rows -> <=4-way bank conflict on frag reads

typedef unsigned short u16;
typedef __attribute__((ext_vector_type(8))) short bf8;     // 8 bf16 (4 VGPRs)
typedef __attribute__((ext_vector_type(4))) float f32x4;

__device__ inline float b2f(u16 v) { return __uint_as_float(((unsigned)v) << 16); }
__device__ inline u16 f2b(float f) {
    unsigned u = __float_as_uint(f);
    return (u16)((u + 0x7FFF + ((u >> 16) & 1)) >> 16);   // RN-even
}
__device__ inline bf8 ldb8(const u16* p) {   // 16B from 8B-aligned LDS (2x b64)
    union { uint2 a[2]; bf8 v; } u;
    u.a[0] = *(const uint2*)p;
    u.a[1] = *(const uint2*)(p + 4);
    return u.v;
}

// ---------------------------------------------------------------- fused CSR fill (XCD-range partitioned)
__global__ __launch_bounds__(256) void k_fill(const int* __restrict__ ei,
                                              int* __restrict__ deg,
                                              int* __restrict__ col) {
    int rangeId = blockIdx.x & 7, chunk = blockIdx.x >> 3;
    int lo = rangeId * (NNODES / 8), hi = lo + (NNODES / 8);
    int ebeg = chunk * (NEDGES / 256), eend = ebeg + (NEDGES / 256);
    for (int e = ebeg + threadIdx.x; e < eend; e += 256) {
        int dst = ei[NEDGES + e];
        if (dst >= lo && dst < hi) {
            int slot = atomicAdd(&deg[dst], 1);
            if (slot < CAP) col[dst * CAP + slot] = ei[e];
        }
    }
}

// ---------------------------------------------------------------- graph start offsets (batch sorted)
__global__ __launch_bounds__(256) void k_goff(const int* __restrict__ batch,
                                              int* __restrict__ gstart) {
    int gph = blockIdx.x * 256 + threadIdx.x;
    if (gph > NGRAPHS) return;
    if (gph == NGRAPHS) { gstart[NGRAPHS] = NNODES; return; }
    int lo = 0, hi = NNODES;
    while (lo < hi) {
        int mid = (lo + hi) >> 1;
        if (batch[mid] < gph) lo = mid + 1; else hi = mid;
    }
    gstart[gph] = lo;
}

// ---------------------------------------------------------------- input GEMM -> z0 (bf16) + stats partials
__global__ __launch_bounds__(256) void k_gemm_in(const float* __restrict__ x,
                                                 const float* __restrict__ Wt,
                                                 const float* __restrict__ bt,
                                                 u16* __restrict__ zout,
                                                 float* __restrict__ partials) {
    __shared__ float sW[NFEAT * NHID];   // 32 KB
    __shared__ float sx[16 * NFEAT];     // 8 KB
    __shared__ float ps[4][128];         // 2 KB
    int tid = threadIdx.x;
    const float4* W4 = (const float4*)Wt;
    float4* sW4 = (float4*)sW;
#pragma unroll
    for (int i = 0; i < NFEAT * NHID / 4 / 256; ++i) sW4[i * 256 + tid] = W4[i * 256 + tid];
    int base = blockIdx.x * 16;
    const float4* x4 = (const float4*)(x + (long long)base * NFEAT);
    float4* sx4 = (float4*)sx;
#pragma unroll
    for (int i = 0; i < 16 * NFEAT / 4 / 256; ++i) sx4[i * 256 + tid] = x4[i * 256 + tid];
    __syncthreads();
    int j = tid & 63, q = tid >> 6;
    float b = bt[j];
    float acc[4] = {b, b, b, b};
    for (int k = 0; k < NFEAT; ++k) {
        float wv = sW[k * NHID + j];
#pragma unroll
        for (int i = 0; i < 4; ++i) acc[i] += sx[(q * 4 + i) * NFEAT + k] * wv;
    }
    float s1 = 0.f, s2 = 0.f;
#pragma unroll
    for (int i = 0; i < 4; ++i) {
        zout[(base + q * 4 + i) * NHID + j] = f2b(acc[i]);
        s1 += acc[i];
        s2 += acc[i] * acc[i];
    }
    ps[q][j] = s1;
    ps[q][64 + j] = s2;
    __syncthreads();
    if (tid < 128)
        partials[blockIdx.x * 128 + tid] = ps[0][tid] + ps[1][tid] + ps[2][tid] + ps[3][tid];
}

// ---------------------------------------------------------------- reduce partials -> stats[128] (sum | sumsq)
__global__ __launch_bounds__(256) void k_red(const float* __restrict__ partials,
                                             float* __restrict__ stats) {
    __shared__ float red[4];
    int c = blockIdx.x, t = threadIdx.x;
    float s = 0.f;
    for (int i = t; i < NPART; i += 256) s += partials[i * 128 + c];
#pragma unroll
    for (int off = 32; off >= 1; off >>= 1) s += __shfl_xor(s, off, 64);
    if ((t & 63) == 0) red[t >> 6] = s;
    __syncthreads();
    if (t == 0) stats[c] = red[0] + red[1] + red[2] + red[3];
}

// ---------------------------------------------------------------- pool per graph, BN applied on the fly (bf16 z)
template <int RELU>
__global__ __launch_bounds__(256) void k_pool(const u16* __restrict__ z,
                                              const float* __restrict__ stats,
                                              const float* __restrict__ gamma,
                                              const float* __restrict__ beta,
                                              const int* __restrict__ gstart,
                                              float* __restrict__ out) {
    __shared__ float red[4][64];
    int gph = blockIdx.x;
    int j = threadIdx.x & 63, sub = threadIdx.x >> 6;
    float m = stats[j] * (1.0f / NNODES);
    float var = stats[64 + j] * (1.0f / NNODES) - m * m;
    float sc = rsqrtf(var + BN_EPS) * gamma[j];
    float sh = beta[j] - m * sc;
    int s0 = gstart[gph], e0 = gstart[gph + 1];
    float s = 0.f;
    for (int r = s0 + sub; r < e0; r += 4) {
        float v = fmaf(b2f(z[r * NHID + j]), sc, sh);
        if (RELU) v = fmaxf(v, 0.f);
        s += v;
    }
    red[sub][j] = s;
    __syncthreads();
    if (sub == 0) {
        s = red[0][j] + red[1][j] + red[2][j] + red[3][j];
        out[gph * NHID + j] = s / fmaxf((float)(e0 - s0), 1.0f);
    }
}

// ---------------------------------------------------------------- fused gather(+inline BN) + MFMA MLP + stats partials
template <int RELU_IN>
__global__ __launch_bounds__(256) void k_mlp(const u16* __restrict__ zin,
                                             const float* __restrict__ stats,
                                             const float* __restrict__ gamma,
                                             const float* __restrict__ beta,
                                             const int* __restrict__ deg,
                                             const int* __restrict__ col,
                                             const float* __restrict__ W1,
                                             const float* __restrict__ b1,
                                             const float* __restrict__ W2,
                                             const float* __restrict__ b2,
                                             u16* __restrict__ zout,
                                             float* __restrict__ partials) {
    __shared__ u16 sW1t[NHID][PADW];   // W1 transposed [n][k] bf16, 8.5 KB
    __shared__ u16 sW2t[NHID][PADW];   // 8.5 KB
    __shared__ u16 szb[16][PADW];      // gathered z (BN'd) bf16 [node][k], 2.125 KB
    __shared__ u16 stb[16][PADW];      // relu(z@W1+b1) bf16, 2.125 KB
    __shared__ float ps[128];          // 0.5 KB
    int tid = threadIdx.x;

    // stage W1,W2 transposed -> bf16 LDS (one-time scattered u16 writes)
    {
        const float4* W14 = (const float4*)W1;
        const float4* W24 = (const float4*)W2;
#pragma unroll
        for (int i = 0; i < 4; ++i) {
            int idx = i * 256 + tid;            // 0..1023 float4s
            int k = idx >> 4, n0 = (idx & 15) * 4;
            float4 v1 = W14[idx], v2 = W24[idx];
            sW1t[n0 + 0][k] = f2b(v1.x); sW1t[n0 + 1][k] = f2b(v1.y);
            sW1t[n0 + 2][k] = f2b(v1.z); sW1t[n0 + 3][k] = f2b(v1.w);
            sW2t[n0 + 0][k] = f2b(v2.x); sW2t[n0 + 1][k] = f2b(v2.y);
            sW2t[n0 + 2][k] = f2b(v2.z); sW2t[n0 + 3][k] = f2b(v2.w);
        }
    }

    int w = tid >> 6, lane = tid & 63;
    int q = lane >> 4, c = lane & 15;
    int node = w * 4 + q;
    int base = blockIdx.x * 16;
    int r = base + node;
    const ushort4* h8 = (const ushort4*)zin;

    // BN coefficients for this lane's 4 features
    int j0 = c * 4;
    float sc[4], sh[4];
#pragma unroll
    for (int k = 0; k < 4; ++k) {
        int j = j0 + k;
        float m = stats[j] * (1.0f / NNODES);
        float var = stats[64 + j] * (1.0f / NNODES) - m * m;
        sc[k] = rsqrtf(var + BN_EPS) * gamma[j];
        sh[k] = beta[j] - m * sc[k];
    }

#define BN1(vv, kk, dstv)                                  \
    {                                                      \
        float u = fmaf(b2f(vv), sc[kk], sh[kk]);           \
        if (RELU_IN) u = fmaxf(u, 0.f);                    \
        dstv += u;                                         \
    }
#define BN4(v4, dst)                                       \
    BN1(v4.x, 0, dst[0]) BN1(v4.y, 1, dst[1])              \
    BN1(v4.z, 2, dst[2]) BN1(v4.w, 3, dst[3])

    // gather: quarter-wave per node, bf16 rows (8 B/lane), 8 loads in flight
    float aA[4] = {0, 0, 0, 0}, aB[4] = {0, 0, 0, 0};
    {
        ushort4 v = h8[r * 16 + c];       // self (also BN'd)
        BN4(v, aA)
    }
    {
        int dd = deg[r]; if (dd > CAP) dd = CAP;
        const int* cp = col + r * CAP;
        int t = 0;
        for (; t + 8 <= dd; t += 8) {
            int s0 = cp[t],     s1 = cp[t + 1], s2 = cp[t + 2], s3 = cp[t + 3];
            int s4 = cp[t + 4], s5 = cp[t + 5], s6 = cp[t + 6], s7 = cp[t + 7];
            ushort4 v0 = h8[s0 * 16 + c];
            ushort4 v1 = h8[s1 * 16 + c];
            ushort4 v2 = h8[s2 * 16 + c];
            ushort4 v3 = h8[s3 * 16 + c];
            ushort4 v4 = h8[s4 * 16 + c];
            ushort4 v5 = h8[s5 * 16 + c];
            ushort4 v6 = h8[s6 * 16 + c];
            ushort4 v7 = h8[s7 * 16 + c];
            BN4(v0, aA) BN4(v1, aB) BN4(v2, aA) BN4(v3, aB)
            BN4(v4, aA) BN4(v5, aB) BN4(v6, aA) BN4(v7, aB)
        }
        for (; t < dd; ++t) {
            ushort4 v0 = h8[cp[t] * 16 + c];
            BN4(v0, aA)
        }
    }
#undef BN4
#undef BN1
    // pack 4 bf16 and write to szb[node][c*4..c*4+3] (8B aligned: 136B rows)
    {
        unsigned p0 = (unsigned)f2b(aA[0] + aB[0]) | ((unsigned)f2b(aA[1] + aB[1]) << 16);
        unsigned p1 = (unsigned)f2b(aA[2] + aB[2]) | ((unsigned)f2b(aA[3] + aB[3]) << 16);
        uint2 pk; pk.x = p0; pk.y = p1;
        *(uint2*)&szb[node][c * 4] = pk;
    }
    __syncthreads();   // weights staged + szb complete

    // ---- MFMA phase: wave w owns output cols [w*16, w*16+16) ----
    int m = lane & 15, g = lane >> 4;      // A-row / k-group
    int ncol = w * 16 + m;                 // B/C column
    bf8 A0 = ldb8(&szb[m][g * 8]);
    bf8 A1 = ldb8(&szb[m][32 + g * 8]);
    bf8 B0 = ldb8(&sW1t[ncol][g * 8]);
    bf8 B1 = ldb8(&sW1t[ncol][32 + g * 8]);
    float bb1 = b1[ncol];
    f32x4 c1 = {bb1, bb1, bb1, bb1};
    c1 = __builtin_amdgcn_mfma_f32_16x16x32_bf16(A0, B0, c1, 0, 0, 0);
    c1 = __builtin_amdgcn_mfma_f32_16x16x32_bf16(A1, B1, c1, 0, 0, 0);
    // relu -> stb (C layout: row = g*4+reg, col = ncol)
#pragma unroll
    for (int i = 0; i < 4; ++i) stb[g * 4 + i][ncol] = f2b(fmaxf(c1[i], 0.f));
    __syncthreads();   // stb complete

    bf8 A20 = ldb8(&stb[m][g * 8]);
    bf8 A21 = ldb8(&stb[m][32 + g * 8]);
    bf8 B20 = ldb8(&sW2t[ncol][g * 8]);
    bf8 B21 = ldb8(&sW2t[ncol][32 + g * 8]);
    float bb2 = b2[ncol];
    f32x4 c2 = {bb2, bb2, bb2, bb2};
    c2 = __builtin_amdgcn_mfma_f32_16x16x32_bf16(A20, B20, c2, 0, 0, 0);
    c2 = __builtin_amdgcn_mfma_f32_16x16x32_bf16(A21, B21, c2, 0, 0, 0);

    // stats: sum over nodes (rows) per feature ncol
    float s1 = c2[0] + c2[1] + c2[2] + c2[3];
    float s2 = c2[0] * c2[0] + c2[1] * c2[1] + c2[2] * c2[2] + c2[3] * c2[3];
    s1 += __shfl_xor(s1, 16, 64); s1 += __shfl_xor(s1, 32, 64);
    s2 += __shfl_xor(s2, 16, 64); s2 += __shfl_xor(s2, 32, 64);
    if (lane < 16) {
        ps[w * 16 + lane] = s1;
        ps[64 + w * 16 + lane] = s2;
    }
    // write z' (bf16): row = g*4+reg, col = ncol
#pragma unroll
    for (int i = 0; i < 4; ++i)
        zout[(base + g * 4 + i) * NHID + ncol] = f2b(c2[i]);
    __syncthreads();
    if (tid < 128) partials[blockIdx.x * 128 + tid] = ps[tid];
}

// ----------------------------------------------------------------
extern "C" void kernel_launch(void* const* d_in, const int* in_sizes, int n_in,
                              void* d_out, int out_size, void* d_ws, size_t ws_size,
                              hipStream_t stream) {
    const float* x     = (const float*)d_in[0];
    const int*   ei    = (const int*)d_in[1];
    const int*   batch = (const int*)d_in[2];
    const float* Wt    = (const float*)d_in[3];
    const float* bt    = (const float*)d_in[4];
    const float* gt    = (const float*)d_in[5];
    const float* bet   = (const float*)d_in[6];
    const float* W1    = (const float*)d_in[7];
    const float* b1    = (const float*)d_in[8];
    const float* W2    = (const float*)d_in[9];
    const float* b2    = (const float*)d_in[10];
    const float* g     = (const float*)d_in[11];
    const float* be    = (const float*)d_in[12];
    float* out = (float*)d_out;

    u16* A          = (u16*)d_ws;                   // 50000*64 bf16
    u16* B          = A + NNODES * NHID;            // 50000*64 bf16
    float* partials = (float*)(B + NNODES * NHID);  // 3125*128 f32
    float* stats    = partials + NPART * 128;       // 4 x 128 f32
    int* deg        = (int*)(stats + 4 * 128);      // 50000
    int* col        = deg + NNODES;                 // 50000*64
    int* gstart     = col + NNODES * CAP;           // 513

    hipMemsetAsync(deg, 0, NNODES * sizeof(int), stream);

    // CSR build + graph offsets
    k_fill<<<2048, 256, 0, stream>>>(ei, deg, col);
    k_goff<<<3, 256, 0, stream>>>(batch, gstart);

    // stage 0: input transform -> z0 (bf16) + stats + pool (BN inline, no relu)
    k_gemm_in<<<NPART, 256, 0, stream>>>(x, Wt, bt, A, partials);
    k_red<<<128, 256, 0, stream>>>(partials, stats);
    k_pool<0><<<NGRAPHS, 256, 0, stream>>>(A, stats, gt, bet, gstart, out);

    u16* bufs[2] = {A, B};
    for (int l = 0; l < NLAYER; ++l) {
        u16* zin  = bufs[l & 1];
        u16* zout = bufs[(l + 1) & 1];
        float* st_in  = stats + l * 128;
        float* st_out = stats + (l + 1) * 128;
        const float* gam_in = (l == 0) ? gt : g + (l - 1) * NHID;
        const float* bet_in = (l == 0) ? bet : be + (l - 1) * NHID;
        if (l == 0)
            k_mlp<0><<<NPART, 256, 0, stream>>>(zin, st_in, gam_in, bet_in, deg, col,
                                                W1 + l * NHID * NHID, b1 + l * NHID,
                                                W2 + l * NHID * NHID, b2 + l * NHID, zout, partials);
        else
            k_mlp<1><<<NPART, 256, 0, stream>>>(zin, st_in, gam_in, bet_in, deg, col,
                                                W1 + l * NHID * NHID, b1 + l * NHID,
                                                W2 + l * NHID * NHID, b2 + l * NHID, zout, partials);
        k_red<<<128, 256, 0, stream>>>(partials, st_out);
        k_pool<1><<<NGRAPHS, 256, 0, stream>>>(zout, st_out, g + l * NHID, be + l * NHID, gstart,
                                               out + (l + 1) * NGRAPHS * NHID);
    }
}